// Round 18
// baseline (624.580 us; speedup 1.0000x reference)
//
#include <hip/hip_runtime.h>
#include <hip/hip_bf16.h>

static constexpr int BB   = 32;
static constexpr int TKK  = 1024;
static constexpr int ND   = 1024;   // N = 2*H
static constexpr int ADIM = 512;

typedef __attribute__((ext_vector_type(8))) short bf16x8;
typedef __attribute__((ext_vector_type(4))) float f32x4;

__device__ __forceinline__ float fast_tanh(float x) {
  x = fminf(fmaxf(x, -15.f), 15.f);
  float e = __expf(2.f * x);
  return __fdividef(e - 1.f, e + 1.f);
}

__device__ __forceinline__ short f2bf(float x) {  // RNE f32->bf16
  unsigned u = __float_as_uint(x);
  u += 0x7FFF + ((u >> 16) & 1);
  return (short)(u >> 16);
}

__device__ __forceinline__ void gload_lds16(const void* g, void* l) {
  __builtin_amdgcn_global_load_lds(
      (const __attribute__((address_space(1))) unsigned int*)g,
      (__attribute__((address_space(3))) unsigned int*)l, 16, 0, 0);
}

// K_PRE: blocks 0..8447 = f32->bf16 cvt (r_i, Wr); blocks 8448..8703 = decfea.
__global__ __launch_bounds__(256) void k_pre(const float* __restrict__ r_i,
    const float* __restrict__ Wr, short* __restrict__ rb, short* __restrict__ wb,
    const float* __restrict__ s_t_hat, const float* __restrict__ Wsw,
    const float* __restrict__ Wsb, float* __restrict__ dec) {
  size_t bid = blockIdx.x;
  if (bid < 8448) {
    const float* src;
    short* dst;
    size_t i;
    if (bid < 8192) { src = r_i; dst = rb; i = bid * 256 + threadIdx.x; }
    else            { src = Wr;  dst = wb; i = (bid - 8192) * 256 + threadIdx.x; }
    float4 a = ((const float4*)src)[2 * i];
    float4 b = ((const float4*)src)[2 * i + 1];
    bf16x8 h;
    h[0] = f2bf(a.x); h[1] = f2bf(a.y); h[2] = f2bf(a.z); h[3] = f2bf(a.w);
    h[4] = f2bf(b.x); h[5] = f2bf(b.y); h[6] = f2bf(b.z); h[7] = f2bf(b.w);
    ((bf16x8*)dst)[i] = h;
  } else {
    int db = (int)bid - 8448;
    int b  = db >> 3;
    int n0 = (db & 7) << 7;
    int w = threadIdx.x >> 6, lane = threadIdx.x & 63;
    const float4* s4 = (const float4*)(s_t_hat + (size_t)b * ND);
    float4 sv0 = s4[lane], sv1 = s4[lane + 64], sv2 = s4[lane + 128], sv3 = s4[lane + 192];
    for (int nn = 0; nn < 32; nn++) {
      int n = n0 + w * 32 + nn;
      const float4* w4 = (const float4*)(Wsw + (size_t)n * ND);
      float4 wa = w4[lane], wb2 = w4[lane + 64], wc = w4[lane + 128], wd = w4[lane + 192];
      float acc = sv0.x*wa.x + sv0.y*wa.y + sv0.z*wa.z + sv0.w*wa.w
                + sv1.x*wb2.x + sv1.y*wb2.y + sv1.z*wb2.z + sv1.w*wb2.w
                + sv2.x*wc.x + sv2.y*wc.y + sv2.z*wc.z + sv2.w*wc.w
                + sv3.x*wd.x + sv3.y*wd.y + sv3.z*wd.z + sv3.w*wd.w;
      #pragma unroll
      for (int off = 32; off; off >>= 1) acc += __shfl_down(acc, off);
      if (lane == 0) dec[b * ND + n] = acc + Wsb[n];
    }
  }
}

// K1 standalone (fallback path)
__global__ __launch_bounds__(256) void k_decfea(const float* __restrict__ s_t_hat,
    const float* __restrict__ Wsw, const float* __restrict__ Wsb,
    float* __restrict__ dec) {
  int b  = blockIdx.x >> 3;
  int n0 = (blockIdx.x & 7) << 7;
  int w = threadIdx.x >> 6, lane = threadIdx.x & 63;
  const float4* s4 = (const float4*)(s_t_hat + (size_t)b * ND);
  float4 sv0 = s4[lane], sv1 = s4[lane + 64], sv2 = s4[lane + 128], sv3 = s4[lane + 192];
  for (int nn = 0; nn < 32; nn++) {
    int n = n0 + w * 32 + nn;
    const float4* w4 = (const float4*)(Wsw + (size_t)n * ND);
    float4 wa = w4[lane], wb = w4[lane + 64], wc = w4[lane + 128], wd = w4[lane + 192];
    float acc = sv0.x*wa.x + sv0.y*wa.y + sv0.z*wa.z + sv0.w*wa.w
              + sv1.x*wb.x + sv1.y*wb.y + sv1.z*wb.z + sv1.w*wb.w
              + sv2.x*wc.x + sv2.y*wc.y + sv2.z*wc.z + sv2.w*wc.w
              + sv3.x*wd.x + sv3.y*wd.y + sv3.z*wd.z + sv3.w*wd.w;
    #pragma unroll
    for (int off = 32; off; off >>= 1) acc += __shfl_down(acc, off);
    if (lane == 0) dec[b * ND + n] = acc + Wsb[n];
  }
}

// K2 standalone (fallback path only)
__global__ __launch_bounds__(256) void k_scoresA(const float* __restrict__ ef,
    const float* __restrict__ dec, const float* __restrict__ Wc,
    const float* __restrict__ vw, const float* __restrict__ cov,
    float* __restrict__ scores) {
  const int bt = blockIdx.x * 4 + (threadIdx.x >> 6);
  const int b  = bt >> 10;
  const int lane = threadIdx.x & 63;
  const float c = cov[bt];
  float s = 0.f;
  #pragma unroll
  for (int q = 0; q < 4; ++q) {
    const int col = q * 256 + lane * 4;
    float4 e = *(const float4*)(ef + (size_t)bt * ND + col);
    float4 d = *(const float4*)(dec + (size_t)b * ND + col);
    float4 w = *(const float4*)(Wc + col);
    float4 v = *(const float4*)(vw + col);
    s += v.x * fast_tanh(e.x + d.x + c * w.x)
       + v.y * fast_tanh(e.y + d.y + c * w.y)
       + v.z * fast_tanh(e.z + d.z + c * w.z)
       + v.w * fast_tanh(e.w + d.w + c * w.w);
  }
  #pragma unroll
  for (int off = 32; off; off >>= 1) s += __shfl_down(s, off);
  if (lane == 0) scores[bt] = s;
}

// MEGA v3: grid 8192, even bid -> gemm (4096 blocks, K SPLIT in halves of 256),
// odd bid -> scoresA (4096 blocks, 2 rows/wave). Gemm: 128x128xK256, 8 K-iters,
// 3-slot ring, counted vmcnt. part slot = nchunk*4 + wn*2 + kh (32 slots/row).
__global__ __launch_bounds__(256) void k_mega(const short* __restrict__ rb,
    const short* __restrict__ wb, const float* __restrict__ dec,
    const float* __restrict__ vw, float* __restrict__ part,
    const float* __restrict__ ef, const float* __restrict__ Wc,
    const float* __restrict__ cov, float* __restrict__ scores) {
  if ((blockIdx.x & 1) == 0) {
    const int gid = blockIdx.x >> 1;               // 0..4095
    __shared__ __align__(16) short As[3][128 * 32];
    __shared__ __align__(16) short Bs[3][128 * 32];
    const int tid = threadIdx.x;
    const int lane = tid & 63, wv = tid >> 6;
    const int wm = wv >> 1, wn = wv & 1;
    const int g = lane >> 4, cl = lane & 15;
    const int swz = (gid & 7) * 512 + (gid >> 3);  // XCD-bijective (4096%8==0)
    const int mchunk = swz >> 4;                   // 0..255
    const int nchunk = (swz >> 1) & 7;             // 0..7
    const int kh     = swz & 1;                    // K half
    const int b  = mchunk >> 3;
    const int t0 = (mchunk & 7) * 128;
    const int n0 = nchunk * 128;
    const int kbase = kh * 256;
    const int lrow4 = lane >> 2;
    const int sck   = ((lane & 3) ^ ((lane >> 3) & 3)) * 8;
    const short* Agbase = rb + (size_t)(b * TKK + t0) * ADIM + kbase;
    const short* Bgbase = wb + (size_t)n0 * ADIM + kbase;
    const int rdsw = (g ^ ((cl >> 1) & 3)) * 8;

    f32x4 acc[4][4];
    #pragma unroll
    for (int m = 0; m < 4; ++m)
      #pragma unroll
      for (int n = 0; n < 4; ++n) acc[m][n] = (f32x4){0.f, 0.f, 0.f, 0.f};

    auto stage = [&](int buf, int kc) {
      const int k0 = kc * 32;
      #pragma unroll
      for (int p = 0; p < 2; ++p) {
        const int rowc = p * 64 + wv * 16;
        const int row  = rowc + lrow4;
        gload_lds16(Agbase + (size_t)row * ADIM + k0 + sck, &As[buf][rowc * 32]);
        gload_lds16(Bgbase + (size_t)row * ADIM + k0 + sck, &Bs[buf][rowc * 32]);
      }
    };

    stage(0, 0);
    stage(1, 1);
    for (int kc = 0; kc < 8; ++kc) {
      if (kc < 6) {
        stage((kc + 2) % 3, kc + 2);
        asm volatile("s_waitcnt vmcnt(8)" ::: "memory");
      } else if (kc == 6) {
        asm volatile("s_waitcnt vmcnt(4)" ::: "memory");
      } else {
        asm volatile("s_waitcnt vmcnt(0)" ::: "memory");
      }
      __builtin_amdgcn_s_barrier();
      const int cur = kc % 3;
      bf16x8 af[4], bfr[4];
      #pragma unroll
      for (int m = 0; m < 4; ++m)
        af[m] = *(const bf16x8*)&As[cur][(wm * 64 + m * 16 + cl) * 32 + rdsw];
      #pragma unroll
      for (int n = 0; n < 4; ++n)
        bfr[n] = *(const bf16x8*)&Bs[cur][(wn * 64 + n * 16 + cl) * 32 + rdsw];
      #pragma unroll
      for (int m = 0; m < 4; ++m)
        #pragma unroll
        for (int n = 0; n < 4; ++n)
          acc[m][n] = __builtin_amdgcn_mfma_f32_16x16x32_bf16(af[m], bfr[n], acc[m][n], 0, 0, 0);
      __builtin_amdgcn_s_barrier();
    }

    // NOTE: no dec/tanh here — K-half partial sums are linear; epilogue moves
    // to softmaxB (needs full K sum before tanh). Store raw dot products.
    #pragma unroll
    for (int m = 0; m < 4; ++m) {
      #pragma unroll
      for (int r = 0; r < 4; ++r) {
        // Emit per (row, 16-col group): reduce acc over n? No — tanh is per
        // col; we must keep per-col values. Instead apply v[n]*tanh later.
        // Each lane holds cols n*16+cl, row = wm*64+m*16+g*4+r. We need the
        // full-K dot before tanh, so store per-col partial dot:
        // layout part2[row][col][kh] is too big (64 MB). Alternative: reduce
        // over K halves via atomic? No. Use the identity: only the SUM over
        // n of v*tanh matters, and tanh needs full K. So: store the 4 n-col
        // values per lane to part2[rowg][nchunk*64 + n*16+cl][kh]? 128 cols
        // per block -> per row 128 values x 2 kh = 32768 rows x 256 = 33 MB
        // f32. That fits ws (we have room) but doubles stream traffic.
        // Simpler: keep kh in part slot and do tanh in softmaxB after
        // summing the two kh entries PER COLUMN GROUP. But columns were
        // already reduced here pre-tanh... cannot. So we must NOT reduce
        // over columns pre-tanh. Fall through below.
      }
    }
    // Store per-column partial dots: cpart[rowg * 256 + (nchunk*16+...)].
    // Each lane stores 16 floats (4 m-frags x 4 regs) for its 4 cols? Layout:
    // cpart[(rowg)][kh*... ] -- see host layout: cpart = part (reused),
    // stride 2*ND per row: col + kh*ND.
    #pragma unroll
    for (int m = 0; m < 4; ++m) {
      #pragma unroll
      for (int r = 0; r < 4; ++r) {
        const int rowg = b * TKK + t0 + wm * 64 + m * 16 + g * 4 + r;
        #pragma unroll
        for (int n = 0; n < 4; ++n) {
          const int col = n0 + wn * 64 + n * 16 + cl;
          part[(size_t)rowg * (2 * ND) + kh * ND + col] = acc[m][n][r];
        }
      }
    }
  } else {
    // scoresA: sidx 0..4095, 2 rows per wave
    const int sidx = blockIdx.x >> 1;
    const int bt0 = sidx * 8 + (threadIdx.x >> 6) * 2;
    const int lane = threadIdx.x & 63;
    const int b0 = bt0 >> 10, b1 = (bt0 + 1) >> 10;
    const float c0 = cov[bt0], c1 = cov[bt0 + 1];
    float s0 = 0.f, s1 = 0.f;
    #pragma unroll
    for (int q = 0; q < 4; ++q) {
      const int col = q * 256 + lane * 4;
      float4 e0 = *(const float4*)(ef + (size_t)bt0 * ND + col);
      float4 e1 = *(const float4*)(ef + (size_t)(bt0 + 1) * ND + col);
      float4 d0 = *(const float4*)(dec + (size_t)b0 * ND + col);
      float4 d1 = *(const float4*)(dec + (size_t)b1 * ND + col);
      float4 w = *(const float4*)(Wc + col);
      float4 v = *(const float4*)(vw + col);
      s0 += v.x * fast_tanh(e0.x + d0.x + c0 * w.x)
          + v.y * fast_tanh(e0.y + d0.y + c0 * w.y)
          + v.z * fast_tanh(e0.z + d0.z + c0 * w.z)
          + v.w * fast_tanh(e0.w + d0.w + c0 * w.w);
      s1 += v.x * fast_tanh(e1.x + d1.x + c1 * w.x)
          + v.y * fast_tanh(e1.y + d1.y + c1 * w.y)
          + v.z * fast_tanh(e1.z + d1.z + c1 * w.z)
          + v.w * fast_tanh(e1.w + d1.w + c1 * w.w);
    }
    #pragma unroll
    for (int off = 32; off; off >>= 1) {
      s0 += __shfl_down(s0, off);
      s1 += __shfl_down(s1, off);
    }
    if (lane == 0) {
      scores[bt0]     = s0;
      scores[bt0 + 1] = s1;
    }
  }
}

// K4 fallback (reg-staged cvt in-kernel) — used only if ws too small.
__global__ __launch_bounds__(256) void k_gemmB(const float* __restrict__ r_i,
    const float* __restrict__ Wr, const float* __restrict__ dec,
    const float* __restrict__ vw, float* __restrict__ part) {
  __shared__ short As[128 * 64];
  __shared__ short Bs[128 * 64];
  const int tid = threadIdx.x;
  const int lane = tid & 63, wv = tid >> 6;
  const int wm = wv >> 1, wn = wv & 1;
  const int g = lane >> 4, cl = lane & 15;
  const int mchunk = blockIdx.x, nchunk = blockIdx.y;
  const int b  = mchunk >> 3;
  const int t0 = (mchunk & 7) * 128;
  const int n0 = nchunk * 128;
  const float* Ag = r_i + (size_t)(b * TKK + t0) * ADIM;
  const float* Bg = Wr + (size_t)n0 * ADIM;
  const int srow = tid >> 3, skk = (tid & 7) * 8;

  f32x4 acc[4][4];
  #pragma unroll
  for (int m = 0; m < 4; ++m)
    #pragma unroll
    for (int n = 0; n < 4; ++n) acc[m][n] = (f32x4){0.f, 0.f, 0.f, 0.f};

  for (int kc = 0; kc < 8; ++kc) {
    const int k0 = kc * 64;
    __syncthreads();
    #pragma unroll
    for (int dit = 0; dit < 4; ++dit) {
      const int row = dit * 32 + srow;
      const float* sa = Ag + (size_t)row * ADIM + k0 + skk;
      float4 a0 = *(const float4*)sa, a1 = *(const float4*)(sa + 4);
      bf16x8 ha;
      ha[0]=f2bf(a0.x); ha[1]=f2bf(a0.y); ha[2]=f2bf(a0.z); ha[3]=f2bf(a0.w);
      ha[4]=f2bf(a1.x); ha[5]=f2bf(a1.y); ha[6]=f2bf(a1.z); ha[7]=f2bf(a1.w);
      *(bf16x8*)&As[row * 64 + skk] = ha;
      const float* sbp = Bg + (size_t)row * ADIM + k0 + skk;
      float4 b0 = *(const float4*)sbp, b1 = *(const float4*)(sbp + 4);
      bf16x8 hb;
      hb[0]=f2bf(b0.x); hb[1]=f2bf(b0.y); hb[2]=f2bf(b0.z); hb[3]=f2bf(b0.w);
      hb[4]=f2bf(b1.x); hb[5]=f2bf(b1.y); hb[6]=f2bf(b1.z); hb[7]=f2bf(b1.w);
      *(bf16x8*)&Bs[row * 64 + skk] = hb;
    }
    __syncthreads();
    #pragma unroll
    for (int kf = 0; kf < 2; ++kf) {
      bf16x8 af[4], bfr[4];
      #pragma unroll
      for (int m = 0; m < 4; ++m)
        af[m] = *(const bf16x8*)&As[(wm * 64 + m * 16 + cl) * 64 + kf * 32 + g * 8];
      #pragma unroll
      for (int n = 0; n < 4; ++n)
        bfr[n] = *(const bf16x8*)&Bs[(wn * 64 + n * 16 + cl) * 64 + kf * 32 + g * 8];
      #pragma unroll
      for (int m = 0; m < 4; ++m)
        #pragma unroll
        for (int n = 0; n < 4; ++n)
          acc[m][n] = __builtin_amdgcn_mfma_f32_16x16x32_bf16(af[m], bfr[n], acc[m][n], 0, 0, 0);
    }
  }
  float vvv[4], ddd[4];
  #pragma unroll
  for (int n = 0; n < 4; ++n) {
    const int col = n0 + wn * 64 + n * 16 + cl;
    vvv[n] = vw[col];
    ddd[n] = dec[b * ND + col];
  }
  #pragma unroll
  for (int m = 0; m < 4; ++m) {
    #pragma unroll
    for (int r = 0; r < 4; ++r) {
      float s = 0.f;
      #pragma unroll
      for (int n = 0; n < 4; ++n)
        s += vvv[n] * fast_tanh(acc[m][n][r] + ddd[n]);
      #pragma unroll
      for (int off = 1; off < 16; off <<= 1) s += __shfl_xor(s, off);
      if (cl == 0) {
        // fallback path keeps old 16-slot layout; softmaxB fallback reads it
        const int rowg = b * TKK + t0 + wm * 64 + m * 16 + g * 4 + r;
        part[(size_t)rowg * (2 * ND) + ND + nchunk * 2 + wn] = s;  // kh=1 plane, slots 0..15
      }
    }
  }
}

// K5 fused: blocks 0..31 -> softmaxA; blocks 32..63 -> softmaxB.
// softmaxB (fast path): s2[row] = sum_col v[col]*tanh(cp0[col]+cp1[col]+dec[col])
template <int FASTB>
__global__ __launch_bounds__(256) void k_softmaxAB(const float* __restrict__ scores,
    const float* __restrict__ part, const float* __restrict__ mask,
    const float* __restrict__ cov, const float* __restrict__ dec,
    const float* __restrict__ vw, float* __restrict__ attn,
    float* __restrict__ covnew, float* __restrict__ astruct) {
  __shared__ float sb[4];
  __shared__ float srow[1024];
  int tid = threadIdx.x;
  if (blockIdx.x < 32) {
    int b = blockIdx.x;
    float4 s = *(const float4*)(scores + (size_t)b * TKK + tid * 4);
    float m = fmaxf(fmaxf(s.x, s.y), fmaxf(s.z, s.w));
    #pragma unroll
    for (int off = 32; off; off >>= 1) m = fmaxf(m, __shfl_down(m, off));
    if ((tid & 63) == 0) sb[tid >> 6] = m;
    __syncthreads();
    m = fmaxf(fmaxf(sb[0], sb[1]), fmaxf(sb[2], sb[3]));
    float4 mk = *(const float4*)(mask + (size_t)b * TKK + tid * 4);
    float4 e;
    e.x = __expf(s.x - m) * mk.x;
    e.y = __expf(s.y - m) * mk.y;
    e.z = __expf(s.z - m) * mk.z;
    e.w = __expf(s.w - m) * mk.w;
    float sum = e.x + e.y + e.z + e.w;
    #pragma unroll
    for (int off = 32; off; off >>= 1) sum += __shfl_down(sum, off);
    __syncthreads();
    if ((tid & 63) == 0) sb[tid >> 6] = sum;
    __syncthreads();
    float inv = __fdividef(1.f, sb[0] + sb[1] + sb[2] + sb[3]);
    float4 a = {e.x * inv, e.y * inv, e.z * inv, e.w * inv};
    *(float4*)(attn + (size_t)b * TKK + tid * 4) = a;
    float4 c = *(const float4*)(cov + (size_t)b * TKK + tid * 4);
    float4 cn = {c.x + a.x, c.y + a.y, c.z + a.z, c.w + a.w};
    *(float4*)(covnew + (size_t)b * TKK + tid * 4) = cn;
  } else {
    int b = blockIdx.x - 32;
    float sv[4];
    if (FASTB) {
      // each wave computes one row's s2 (4 rows per pass, 4 passes = 16 rows)
      // -> too slow serially; instead: 256 threads cooperate per row over 1024
      // rows? Rows = 1024 per b. Do rows in chunks: thread tid handles col
      // tid*4..+3 per row; wave-reduce. 1024 rows x (load 2KB + reduce) —
      // heavy for 32 blocks; use 4 rows concurrently (one per wave).
      for (int tt = 0; tt < 4; ++tt) {
        const int row = (tid >> 6) + 4 * ((tid & 63) >> 6);  // placeholder
      }
      // NOTE: implemented below via per-wave rows loop
      const int lane = tid & 63, wvv = tid >> 6;
      for (int r0 = wvv; r0 < TKK; r0 += 4) {
        const size_t rowg = (size_t)b * TKK + r0;
        const float* cp = part + rowg * (2 * ND);
        float s = 0.f;
        #pragma unroll
        for (int q = 0; q < 4; ++q) {
          const int col = q * 256 + lane * 4;
          float4 p0 = *(const float4*)(cp + col);
          float4 p1 = *(const float4*)(cp + ND + col);
          float4 d  = *(const float4*)(dec + (size_t)b * ND + col);
          float4 v  = *(const float4*)(vw + col);
          s += v.x * fast_tanh(p0.x + p1.x + d.x)
             + v.y * fast_tanh(p0.y + p1.y + d.y)
             + v.z * fast_tanh(p0.z + p1.z + d.z)
             + v.w * fast_tanh(p0.w + p1.w + d.w);
        }
        #pragma unroll
        for (int off = 32; off; off >>= 1) s += __shfl_down(s, off);
        if (lane == 0) srow[r0] = s;
      }
      __syncthreads();
      sv[0] = srow[tid * 4 + 0];
      sv[1] = srow[tid * 4 + 1];
      sv[2] = srow[tid * 4 + 2];
      sv[3] = srow[tid * 4 + 3];
    } else {
      #pragma unroll
      for (int tt = 0; tt < 4; ++tt) {
        const float* pp = part + ((size_t)b * TKK + tid * 4 + tt) * (2 * ND) + ND;
        float s = 0.f;
        for (int q = 0; q < 16; ++q) s += pp[q];
        sv[tt] = s;
      }
    }
    float m = fmaxf(fmaxf(sv[0], sv[1]), fmaxf(sv[2], sv[3]));
    #pragma unroll
    for (int off = 32; off; off >>= 1) m = fmaxf(m, __shfl_down(m, off));
    if ((tid & 63) == 0) sb[tid >> 6] = m;
    __syncthreads();
    m = fmaxf(fmaxf(sb[0], sb[1]), fmaxf(sb[2], sb[3]));
    float e0 = __expf(sv[0] - m), e1 = __expf(sv[1] - m);
    float e2 = __expf(sv[2] - m), e3 = __expf(sv[3] - m);
    float sum = e0 + e1 + e2 + e3;
    #pragma unroll
    for (int off = 32; off; off >>= 1) sum += __shfl_down(sum, off);
    __syncthreads();
    if ((tid & 63) == 0) sb[tid >> 6] = sum;
    __syncthreads();
    float inv = __fdividef(1.f, sb[0] + sb[1] + sb[2] + sb[3]);
    float4 mk = *(const float4*)(mask + (size_t)b * TKK + tid * 4);
    float4 a = {e0 * mk.x * inv, e1 * mk.y * inv, e2 * mk.z * inv, e3 * mk.w * inv};
    *(float4*)(astruct + (size_t)b * TKK + tid * 4) = a;
  }
}

// K6: partial contexts over 32 t-chunks of 32 rows; grid (32, BB).
__global__ __launch_bounds__(256) void k_ctx(const float* __restrict__ enc,
    const float* __restrict__ attn, const float* __restrict__ astr,
    float* __restrict__ partials) {
  int tc = blockIdx.x, b = blockIdx.y;     // tc 0..31
  int tid = threadIdx.x, lane = tid & 63;
  const float4* e4 = (const float4*)(enc + (size_t)(b * TKK + tc * 32) * ND);
  float a1v = attn[(size_t)b * TKK + tc * 32 + (lane & 31)];
  float a2v = astr[(size_t)b * TKK + tc * 32 + (lane & 31)];
  float4 ac = {0, 0, 0, 0}, as = {0, 0, 0, 0};
  #pragma unroll 8
  for (int m = 0; m < 32; m++) {
    float a1 = __shfl(a1v, m), a2 = __shfl(a2v, m);
    float4 ev = e4[(size_t)m * 256 + tid];
    ac.x += a1 * ev.x; ac.y += a1 * ev.y; ac.z += a1 * ev.z; ac.w += a1 * ev.w;
    as.x += a2 * ev.x; as.y += a2 * ev.y; as.z += a2 * ev.z; as.w += a2 * ev.w;
  }
  float* p = partials + (size_t)(b * 32 + tc) * 2 * ND;
  *(float4*)(p + tid * 4) = ac;
  *(float4*)(p + ND + tid * 4) = as;
}

// K7: sum 32 t-chunk partials -> c_t, c_t_struct.  grid (BB, 4).
__global__ __launch_bounds__(256) void k_reduce(const float* __restrict__ partials,
    float* __restrict__ ct, float* __restrict__ cts) {
  int b = blockIdx.x, cx = blockIdx.y;
  int col = cx * 256 + threadIdx.x;
  float sc = 0.f, ss = 0.f;
  for (int tc = 0; tc < 32; tc++) {
    const float* p = partials + (size_t)(b * 32 + tc) * 2 * ND;
    sc += p[col];
    ss += p[ND + col];
  }
  ct[(size_t)b * ND + col] = sc;
  cts[(size_t)b * ND + col] = ss;
}

extern "C" void kernel_launch(void* const* d_in, const int* in_sizes, int n_in,
                              void* d_out, int out_size, void* d_ws, size_t ws_size,
                              hipStream_t stream) {
  const float* s_t_hat = (const float*)d_in[0];
  const float* enc_out  = (const float*)d_in[1];
  const float* enc_feat = (const float*)d_in[2];
  const float* mask     = (const float*)d_in[3];
  const float* cov      = (const float*)d_in[4];
  const float* r_i      = (const float*)d_in[5];
  const float* Wsw      = (const float*)d_in[6];
  const float* Wsb      = (const float*)d_in[7];
  const float* Wc       = (const float*)d_in[8];
  const float* vw       = (const float*)d_in[9];
  const float* Wr       = (const float*)d_in[10];

  float* out    = (float*)d_out;
  float* ct     = out;               // [32,1024]
  float* attn   = out + 32768;       // [32,1024]
  float* covnew = out + 65536;       // [32,1024]
  float* cts    = out + 98304;       // [32,1024]
  float* astr   = out + 131072;      // [32,1,1024]

  float* ws       = (float*)d_ws;
  float* dec      = ws;                      // 32768 f
  float* scores   = ws + 32768;              // 32768 f
  float* cpart    = ws + 65536;              // 32768 rows x 2*ND = 67,108,864 f (268 MB!) -- too big?
  // 32768 * 2048 floats = 67.1M floats = 268 MB. ws fill showed 537 MB total,
  // so it fits, but verify: NEEDED below gates it; fallback otherwise.
  float* partials = cpart + 67108864;        // 2097152 f
  short* rb       = (short*)(partials + 2097152);
  short* wb       = rb + 16777216;
  const size_t NEEDED = ((size_t)32768 + 32768 + 67108864 + 2097152) * 4
                      + (16777216ull + 524288ull) * 2;   // ~311 MB

  if (ws_size >= NEEDED) {
    k_pre<<<8704, 256, 0, stream>>>(r_i, Wr, rb, wb, s_t_hat, Wsw, Wsb, dec);
    k_mega<<<8192, 256, 0, stream>>>(rb, wb, dec, vw, cpart,
                                     enc_feat, Wc, cov, scores);
    k_softmaxAB<1><<<64, 256, 0, stream>>>(scores, cpart, mask, cov, dec, vw,
                                           attn, covnew, astr);
  } else {
    k_decfea<<<256, 256, 0, stream>>>(s_t_hat, Wsw, Wsb, dec);
    k_scoresA<<<8192, 256, 0, stream>>>(enc_feat, dec, Wc, vw, cov, scores);
    k_gemmB<<<dim3(256, 8), 256, 0, stream>>>(r_i, Wr, dec, vw, cpart);
    k_softmaxAB<0><<<64, 256, 0, stream>>>(scores, cpart, mask, cov, dec, vw,
                                           attn, covnew, astr);
  }
  k_ctx<<<dim3(32, BB), 256, 0, stream>>>(enc_out, attn, astr, partials);
  k_reduce<<<dim3(BB, 4), 256, 0, stream>>>(partials, ct, cts);
}

// Round 19
// 162.894 us; speedup vs baseline: 3.8343x; 3.8343x over previous
//
#include <hip/hip_runtime.h>
#include <hip/hip_bf16.h>

static constexpr int BB   = 32;
static constexpr int TKK  = 1024;
static constexpr int ND   = 1024;   // N = 2*H
static constexpr int ADIM = 512;

typedef __attribute__((ext_vector_type(8))) short bf16x8;
typedef __attribute__((ext_vector_type(4))) float f32x4;

__device__ __forceinline__ float fast_tanh(float x) {
  x = fminf(fmaxf(x, -15.f), 15.f);
  float e = __expf(2.f * x);
  return __fdividef(e - 1.f, e + 1.f);
}

__device__ __forceinline__ short f2bf(float x) {  // RNE f32->bf16
  unsigned u = __float_as_uint(x);
  u += 0x7FFF + ((u >> 16) & 1);
  return (short)(u >> 16);
}

__device__ __forceinline__ void gload_lds16(const void* g, void* l) {
  __builtin_amdgcn_global_load_lds(
      (const __attribute__((address_space(1))) unsigned int*)g,
      (__attribute__((address_space(3))) unsigned int*)l, 16, 0, 0);
}

// K0: f32 -> bf16 streaming convert for r_i (8192 blocks) and Wr (256 blocks).
__global__ __launch_bounds__(256) void k_cvt2(const float* __restrict__ r_i,
    const float* __restrict__ Wr, short* __restrict__ rb, short* __restrict__ wb) {
  size_t bid = blockIdx.x;
  const float* src;
  short* dst;
  size_t i;
  if (bid < 8192) { src = r_i; dst = rb; i = bid * 256 + threadIdx.x; }
  else            { src = Wr;  dst = wb; i = (bid - 8192) * 256 + threadIdx.x; }
  float4 a = ((const float4*)src)[2 * i];
  float4 b = ((const float4*)src)[2 * i + 1];
  bf16x8 h;
  h[0] = f2bf(a.x); h[1] = f2bf(a.y); h[2] = f2bf(a.z); h[3] = f2bf(a.w);
  h[4] = f2bf(b.x); h[5] = f2bf(b.y); h[6] = f2bf(b.z); h[7] = f2bf(b.w);
  ((bf16x8*)dst)[i] = h;
}

// K1: dec[b][n] = sum_k s_t_hat[b][k] * Wsw[n][k] + Wsb[n]
__global__ __launch_bounds__(256) void k_decfea(const float* __restrict__ s_t_hat,
    const float* __restrict__ Wsw, const float* __restrict__ Wsb,
    float* __restrict__ dec) {
  int b  = blockIdx.x >> 3;
  int n0 = (blockIdx.x & 7) << 7;
  int w = threadIdx.x >> 6, lane = threadIdx.x & 63;
  const float4* s4 = (const float4*)(s_t_hat + (size_t)b * ND);
  float4 sv0 = s4[lane], sv1 = s4[lane + 64], sv2 = s4[lane + 128], sv3 = s4[lane + 192];
  for (int nn = 0; nn < 32; nn++) {
    int n = n0 + w * 32 + nn;
    const float4* w4 = (const float4*)(Wsw + (size_t)n * ND);
    float4 wa = w4[lane], wb = w4[lane + 64], wc = w4[lane + 128], wd = w4[lane + 192];
    float acc = sv0.x*wa.x + sv0.y*wa.y + sv0.z*wa.z + sv0.w*wa.w
              + sv1.x*wb.x + sv1.y*wb.y + sv1.z*wb.z + sv1.w*wb.w
              + sv2.x*wc.x + sv2.y*wc.y + sv2.z*wc.z + sv2.w*wc.w
              + sv3.x*wd.x + sv3.y*wd.y + sv3.z*wd.z + sv3.w*wd.w;
    #pragma unroll
    for (int off = 32; off; off >>= 1) acc += __shfl_down(acc, off);
    if (lane == 0) dec[b * ND + n] = acc + Wsb[n];
  }
}

// K2 standalone (fallback path only)
__global__ __launch_bounds__(256) void k_scoresA(const float* __restrict__ ef,
    const float* __restrict__ dec, const float* __restrict__ Wc,
    const float* __restrict__ vw, const float* __restrict__ cov,
    float* __restrict__ scores) {
  const int bt = blockIdx.x * 4 + (threadIdx.x >> 6);
  const int b  = bt >> 10;
  const int lane = threadIdx.x & 63;
  const float c = cov[bt];
  float s = 0.f;
  #pragma unroll
  for (int q = 0; q < 4; ++q) {
    const int col = q * 256 + lane * 4;
    float4 e = *(const float4*)(ef + (size_t)bt * ND + col);
    float4 d = *(const float4*)(dec + (size_t)b * ND + col);
    float4 w = *(const float4*)(Wc + col);
    float4 v = *(const float4*)(vw + col);
    s += v.x * fast_tanh(e.x + d.x + c * w.x)
       + v.y * fast_tanh(e.y + d.y + c * w.y)
       + v.z * fast_tanh(e.z + d.z + c * w.z)
       + v.w * fast_tanh(e.w + d.w + c * w.w);
  }
  #pragma unroll
  for (int off = 32; off; off >>= 1) s += __shfl_down(s, off);
  if (lane == 0) scores[bt] = s;
}

// MEGA: blocks 0..2047 = R8 gemm (unchanged); blocks 2048..6143 = scoresA
// (2 rows/wave). Compute-bound gemm and BW-bound scoresA share the machine.
__global__ __launch_bounds__(256) void k_mega(const short* __restrict__ rb,
    const short* __restrict__ wb, const float* __restrict__ dec,
    const float* __restrict__ vw, float* __restrict__ part,
    const float* __restrict__ ef, const float* __restrict__ Wc,
    const float* __restrict__ cov, float* __restrict__ scores) {
  if (blockIdx.x < 2048) {
    __shared__ __align__(16) short As[3][128 * 32];
    __shared__ __align__(16) short Bs[3][128 * 32];
    const int tid = threadIdx.x;
    const int lane = tid & 63, wv = tid >> 6;
    const int wm = wv >> 1, wn = wv & 1;
    const int g = lane >> 4, cl = lane & 15;
    const int bid = blockIdx.x;
    const int swz = (bid & 7) * 256 + (bid >> 3);   // XCD-bijective
    const int mchunk = swz >> 3, nchunk = swz & 7;
    const int b  = mchunk >> 3;
    const int t0 = (mchunk & 7) * 128;
    const int n0 = nchunk * 128;
    const int lrow4 = lane >> 2;
    const int sck   = ((lane & 3) ^ ((lane >> 3) & 3)) * 8;
    const short* Agbase = rb + (size_t)(b * TKK + t0) * ADIM;
    const short* Bgbase = wb + (size_t)n0 * ADIM;
    const int rdsw = (g ^ ((cl >> 1) & 3)) * 8;

    f32x4 acc[4][4];
    #pragma unroll
    for (int m = 0; m < 4; ++m)
      #pragma unroll
      for (int n = 0; n < 4; ++n) acc[m][n] = (f32x4){0.f, 0.f, 0.f, 0.f};

    auto stage = [&](int buf, int kc) {
      const int k0 = kc * 32;
      #pragma unroll
      for (int p = 0; p < 2; ++p) {
        const int rowc = p * 64 + wv * 16;
        const int row  = rowc + lrow4;
        gload_lds16(Agbase + (size_t)row * ADIM + k0 + sck, &As[buf][rowc * 32]);
        gload_lds16(Bgbase + (size_t)row * ADIM + k0 + sck, &Bs[buf][rowc * 32]);
      }
    };

    stage(0, 0);
    stage(1, 1);
    for (int kc = 0; kc < 16; ++kc) {
      if (kc < 14) {
        stage((kc + 2) % 3, kc + 2);
        asm volatile("s_waitcnt vmcnt(8)" ::: "memory");
      } else if (kc == 14) {
        asm volatile("s_waitcnt vmcnt(4)" ::: "memory");
      } else {
        asm volatile("s_waitcnt vmcnt(0)" ::: "memory");
      }
      __builtin_amdgcn_s_barrier();
      const int cur = kc % 3;
      bf16x8 af[4], bfr[4];
      #pragma unroll
      for (int m = 0; m < 4; ++m)
        af[m] = *(const bf16x8*)&As[cur][(wm * 64 + m * 16 + cl) * 32 + rdsw];
      #pragma unroll
      for (int n = 0; n < 4; ++n)
        bfr[n] = *(const bf16x8*)&Bs[cur][(wn * 64 + n * 16 + cl) * 32 + rdsw];
      #pragma unroll
      for (int m = 0; m < 4; ++m)
        #pragma unroll
        for (int n = 0; n < 4; ++n)
          acc[m][n] = __builtin_amdgcn_mfma_f32_16x16x32_bf16(af[m], bfr[n], acc[m][n], 0, 0, 0);
      __builtin_amdgcn_s_barrier();
    }

    float vvv[4], ddd[4];
    #pragma unroll
    for (int n = 0; n < 4; ++n) {
      const int col = n0 + wn * 64 + n * 16 + cl;
      vvv[n] = vw[col];
      ddd[n] = dec[b * ND + col];
    }
    #pragma unroll
    for (int m = 0; m < 4; ++m) {
      #pragma unroll
      for (int r = 0; r < 4; ++r) {
        float s = 0.f;
        #pragma unroll
        for (int n = 0; n < 4; ++n)
          s += vvv[n] * fast_tanh(acc[m][n][r] + ddd[n]);
        #pragma unroll
        for (int off = 1; off < 16; off <<= 1) s += __shfl_xor(s, off);
        if (cl == 0) {
          const int rowg = b * TKK + t0 + wm * 64 + m * 16 + g * 4 + r;
          part[(size_t)rowg * 16 + nchunk * 2 + wn] = s;
        }
      }
    }
  } else {
    // scoresA: 2 rows per wave; sbid 0..4095 covers 32768 rows
    const int sbid = blockIdx.x - 2048;
    const int bt0 = sbid * 8 + (threadIdx.x >> 6) * 2;
    const int lane = threadIdx.x & 63;
    const int b0 = bt0 >> 10, b1 = (bt0 + 1) >> 10;
    const float c0 = cov[bt0], c1 = cov[bt0 + 1];
    float s0 = 0.f, s1 = 0.f;
    #pragma unroll
    for (int q = 0; q < 4; ++q) {
      const int col = q * 256 + lane * 4;
      float4 e0 = *(const float4*)(ef + (size_t)bt0 * ND + col);
      float4 e1 = *(const float4*)(ef + (size_t)(bt0 + 1) * ND + col);
      float4 d0 = *(const float4*)(dec + (size_t)b0 * ND + col);
      float4 d1 = *(const float4*)(dec + (size_t)b1 * ND + col);
      float4 w = *(const float4*)(Wc + col);
      float4 v = *(const float4*)(vw + col);
      s0 += v.x * fast_tanh(e0.x + d0.x + c0 * w.x)
          + v.y * fast_tanh(e0.y + d0.y + c0 * w.y)
          + v.z * fast_tanh(e0.z + d0.z + c0 * w.z)
          + v.w * fast_tanh(e0.w + d0.w + c0 * w.w);
      s1 += v.x * fast_tanh(e1.x + d1.x + c1 * w.x)
          + v.y * fast_tanh(e1.y + d1.y + c1 * w.y)
          + v.z * fast_tanh(e1.z + d1.z + c1 * w.z)
          + v.w * fast_tanh(e1.w + d1.w + c1 * w.w);
    }
    #pragma unroll
    for (int off = 32; off; off >>= 1) {
      s0 += __shfl_down(s0, off);
      s1 += __shfl_down(s1, off);
    }
    if (lane == 0) {
      scores[bt0]     = s0;
      scores[bt0 + 1] = s1;
    }
  }
}

// K4 fallback (reg-staged cvt in-kernel) — used only if ws too small.
__global__ __launch_bounds__(256) void k_gemmB(const float* __restrict__ r_i,
    const float* __restrict__ Wr, const float* __restrict__ dec,
    const float* __restrict__ vw, float* __restrict__ part) {
  __shared__ short As[128 * 64];
  __shared__ short Bs[128 * 64];
  const int tid = threadIdx.x;
  const int lane = tid & 63, wv = tid >> 6;
  const int wm = wv >> 1, wn = wv & 1;
  const int g = lane >> 4, cl = lane & 15;
  const int mchunk = blockIdx.x, nchunk = blockIdx.y;
  const int b  = mchunk >> 3;
  const int t0 = (mchunk & 7) * 128;
  const int n0 = nchunk * 128;
  const float* Ag = r_i + (size_t)(b * TKK + t0) * ADIM;
  const float* Bg = Wr + (size_t)n0 * ADIM;
  const int srow = tid >> 3, skk = (tid & 7) * 8;

  f32x4 acc[4][4];
  #pragma unroll
  for (int m = 0; m < 4; ++m)
    #pragma unroll
    for (int n = 0; n < 4; ++n) acc[m][n] = (f32x4){0.f, 0.f, 0.f, 0.f};

  for (int kc = 0; kc < 8; ++kc) {
    const int k0 = kc * 64;
    __syncthreads();
    #pragma unroll
    for (int dit = 0; dit < 4; ++dit) {
      const int row = dit * 32 + srow;
      const float* sa = Ag + (size_t)row * ADIM + k0 + skk;
      float4 a0 = *(const float4*)sa, a1 = *(const float4*)(sa + 4);
      bf16x8 ha;
      ha[0]=f2bf(a0.x); ha[1]=f2bf(a0.y); ha[2]=f2bf(a0.z); ha[3]=f2bf(a0.w);
      ha[4]=f2bf(a1.x); ha[5]=f2bf(a1.y); ha[6]=f2bf(a1.z); ha[7]=f2bf(a1.w);
      *(bf16x8*)&As[row * 64 + skk] = ha;
      const float* sbp = Bg + (size_t)row * ADIM + k0 + skk;
      float4 b0 = *(const float4*)sbp, b1 = *(const float4*)(sbp + 4);
      bf16x8 hb;
      hb[0]=f2bf(b0.x); hb[1]=f2bf(b0.y); hb[2]=f2bf(b0.z); hb[3]=f2bf(b0.w);
      hb[4]=f2bf(b1.x); hb[5]=f2bf(b1.y); hb[6]=f2bf(b1.z); hb[7]=f2bf(b1.w);
      *(bf16x8*)&Bs[row * 64 + skk] = hb;
    }
    __syncthreads();
    #pragma unroll
    for (int kf = 0; kf < 2; ++kf) {
      bf16x8 af[4], bfr[4];
      #pragma unroll
      for (int m = 0; m < 4; ++m)
        af[m] = *(const bf16x8*)&As[(wm * 64 + m * 16 + cl) * 64 + kf * 32 + g * 8];
      #pragma unroll
      for (int n = 0; n < 4; ++n)
        bfr[n] = *(const bf16x8*)&Bs[(wn * 64 + n * 16 + cl) * 64 + kf * 32 + g * 8];
      #pragma unroll
      for (int m = 0; m < 4; ++m)
        #pragma unroll
        for (int n = 0; n < 4; ++n)
          acc[m][n] = __builtin_amdgcn_mfma_f32_16x16x32_bf16(af[m], bfr[n], acc[m][n], 0, 0, 0);
    }
  }
  float vvv[4], ddd[4];
  #pragma unroll
  for (int n = 0; n < 4; ++n) {
    const int col = n0 + wn * 64 + n * 16 + cl;
    vvv[n] = vw[col];
    ddd[n] = dec[b * ND + col];
  }
  #pragma unroll
  for (int m = 0; m < 4; ++m) {
    #pragma unroll
    for (int r = 0; r < 4; ++r) {
      float s = 0.f;
      #pragma unroll
      for (int n = 0; n < 4; ++n)
        s += vvv[n] * fast_tanh(acc[m][n][r] + ddd[n]);
      #pragma unroll
      for (int off = 1; off < 16; off <<= 1) s += __shfl_xor(s, off);
      if (cl == 0) {
        const int rowg = b * TKK + t0 + wm * 64 + m * 16 + g * 4 + r;
        part[(size_t)rowg * 16 + nchunk * 2 + wn] = s;
      }
    }
  }
}

// K5 fused: blocks 0..31 -> softmaxA; blocks 32..63 -> softmaxB.
__global__ __launch_bounds__(256) void k_softmaxAB(const float* __restrict__ scores,
    const float* __restrict__ part, const float* __restrict__ mask,
    const float* __restrict__ cov, float* __restrict__ attn,
    float* __restrict__ covnew, float* __restrict__ astruct) {
  __shared__ float sb[4];
  int tid = threadIdx.x;
  if (blockIdx.x < 32) {
    int b = blockIdx.x;
    float4 s = *(const float4*)(scores + (size_t)b * TKK + tid * 4);
    float m = fmaxf(fmaxf(s.x, s.y), fmaxf(s.z, s.w));
    #pragma unroll
    for (int off = 32; off; off >>= 1) m = fmaxf(m, __shfl_down(m, off));
    if ((tid & 63) == 0) sb[tid >> 6] = m;
    __syncthreads();
    m = fmaxf(fmaxf(sb[0], sb[1]), fmaxf(sb[2], sb[3]));
    float4 mk = *(const float4*)(mask + (size_t)b * TKK + tid * 4);
    float4 e;
    e.x = __expf(s.x - m) * mk.x;
    e.y = __expf(s.y - m) * mk.y;
    e.z = __expf(s.z - m) * mk.z;
    e.w = __expf(s.w - m) * mk.w;
    float sum = e.x + e.y + e.z + e.w;
    #pragma unroll
    for (int off = 32; off; off >>= 1) sum += __shfl_down(sum, off);
    __syncthreads();
    if ((tid & 63) == 0) sb[tid >> 6] = sum;
    __syncthreads();
    float inv = __fdividef(1.f, sb[0] + sb[1] + sb[2] + sb[3]);
    float4 a = {e.x * inv, e.y * inv, e.z * inv, e.w * inv};
    *(float4*)(attn + (size_t)b * TKK + tid * 4) = a;
    float4 c = *(const float4*)(cov + (size_t)b * TKK + tid * 4);
    float4 cn = {c.x + a.x, c.y + a.y, c.z + a.z, c.w + a.w};
    *(float4*)(covnew + (size_t)b * TKK + tid * 4) = cn;
  } else {
    int b = blockIdx.x - 32;
    float sv[4];
    #pragma unroll
    for (int tt = 0; tt < 4; ++tt) {
      const float4* pp = (const float4*)(part + ((size_t)b * TKK + tid * 4 + tt) * 16);
      float4 q0 = pp[0], q1 = pp[1], q2 = pp[2], q3 = pp[3];
      sv[tt] = q0.x+q0.y+q0.z+q0.w + q1.x+q1.y+q1.z+q1.w
             + q2.x+q2.y+q2.z+q2.w + q3.x+q3.y+q3.z+q3.w;
    }
    float m = fmaxf(fmaxf(sv[0], sv[1]), fmaxf(sv[2], sv[3]));
    #pragma unroll
    for (int off = 32; off; off >>= 1) m = fmaxf(m, __shfl_down(m, off));
    if ((tid & 63) == 0) sb[tid >> 6] = m;
    __syncthreads();
    m = fmaxf(fmaxf(sb[0], sb[1]), fmaxf(sb[2], sb[3]));
    float e0 = __expf(sv[0] - m), e1 = __expf(sv[1] - m);
    float e2 = __expf(sv[2] - m), e3 = __expf(sv[3] - m);
    float sum = e0 + e1 + e2 + e3;
    #pragma unroll
    for (int off = 32; off; off >>= 1) sum += __shfl_down(sum, off);
    __syncthreads();
    if ((tid & 63) == 0) sb[tid >> 6] = sum;
    __syncthreads();
    float inv = __fdividef(1.f, sb[0] + sb[1] + sb[2] + sb[3]);
    float4 mk = *(const float4*)(mask + (size_t)b * TKK + tid * 4);
    float4 a = {e0 * mk.x * inv, e1 * mk.y * inv, e2 * mk.z * inv, e3 * mk.w * inv};
    *(float4*)(astruct + (size_t)b * TKK + tid * 4) = a;
  }
}

// K6: partial contexts over 32 t-chunks of 32 rows; grid (32, BB).
__global__ __launch_bounds__(256) void k_ctx(const float* __restrict__ enc,
    const float* __restrict__ attn, const float* __restrict__ astr,
    float* __restrict__ partials) {
  int tc = blockIdx.x, b = blockIdx.y;     // tc 0..31
  int tid = threadIdx.x, lane = tid & 63;
  const float4* e4 = (const float4*)(enc + (size_t)(b * TKK + tc * 32) * ND);
  float a1v = attn[(size_t)b * TKK + tc * 32 + (lane & 31)];
  float a2v = astr[(size_t)b * TKK + tc * 32 + (lane & 31)];
  float4 ac = {0, 0, 0, 0}, as = {0, 0, 0, 0};
  #pragma unroll 8
  for (int m = 0; m < 32; m++) {
    float a1 = __shfl(a1v, m), a2 = __shfl(a2v, m);
    float4 ev = e4[(size_t)m * 256 + tid];
    ac.x += a1 * ev.x; ac.y += a1 * ev.y; ac.z += a1 * ev.z; ac.w += a1 * ev.w;
    as.x += a2 * ev.x; as.y += a2 * ev.y; as.z += a2 * ev.z; as.w += a2 * ev.w;
  }
  float* p = partials + (size_t)(b * 32 + tc) * 2 * ND;
  *(float4*)(p + tid * 4) = ac;
  *(float4*)(p + ND + tid * 4) = as;
}

// K7: sum 32 t-chunk partials -> c_t, c_t_struct.  grid (BB, 4).
__global__ __launch_bounds__(256) void k_reduce(const float* __restrict__ partials,
    float* __restrict__ ct, float* __restrict__ cts) {
  int b = blockIdx.x, cx = blockIdx.y;
  int col = cx * 256 + threadIdx.x;
  float sc = 0.f, ss = 0.f;
  for (int tc = 0; tc < 32; tc++) {
    const float* p = partials + (size_t)(b * 32 + tc) * 2 * ND;
    sc += p[col];
    ss += p[ND + col];
  }
  ct[(size_t)b * ND + col] = sc;
  cts[(size_t)b * ND + col] = ss;
}

extern "C" void kernel_launch(void* const* d_in, const int* in_sizes, int n_in,
                              void* d_out, int out_size, void* d_ws, size_t ws_size,
                              hipStream_t stream) {
  const float* s_t_hat = (const float*)d_in[0];
  const float* enc_out  = (const float*)d_in[1];
  const float* enc_feat = (const float*)d_in[2];
  const float* mask     = (const float*)d_in[3];
  const float* cov      = (const float*)d_in[4];
  const float* r_i      = (const float*)d_in[5];
  const float* Wsw      = (const float*)d_in[6];
  const float* Wsb      = (const float*)d_in[7];
  const float* Wc       = (const float*)d_in[8];
  const float* vw       = (const float*)d_in[9];
  const float* Wr       = (const float*)d_in[10];

  float* out    = (float*)d_out;
  float* ct     = out;               // [32,1024]
  float* attn   = out + 32768;       // [32,1024]
  float* covnew = out + 65536;       // [32,1024]
  float* cts    = out + 98304;       // [32,1024]
  float* astr   = out + 131072;      // [32,1,1024]

  float* ws       = (float*)d_ws;
  float* dec      = ws;                      // 32768 f
  float* scores   = ws + 32768;              // 32768 f
  float* s2part   = ws + 65536;              // 524288 f
  float* partials = ws + 589824;             // 2097152 f (32*32*2*1024)
  short* rb       = (short*)(ws + 2686976);  // 16,777,216 bf16 (33.55 MB)
  short* wb       = rb + 16777216;           // 524,288 bf16 (1.05 MB)
  const size_t NEEDED = 2686976ull * 4 + 16777216ull * 2 + 524288ull * 2; // 45,350,912 B

  k_decfea<<<256, 256, 0, stream>>>(s_t_hat, Wsw, Wsb, dec);
  if (ws_size >= NEEDED) {
    k_cvt2<<<8448, 256, 0, stream>>>(r_i, Wr, rb, wb);
    k_mega<<<6144, 256, 0, stream>>>(rb, wb, dec, vw, s2part,
                                     enc_feat, Wc, cov, scores);
  } else {
    k_scoresA<<<8192, 256, 0, stream>>>(enc_feat, dec, Wc, vw, cov, scores);
    k_gemmB<<<dim3(256, 8), 256, 0, stream>>>(r_i, Wr, dec, vw, s2part);
  }
  k_softmaxAB<<<64, 256, 0, stream>>>(scores, s2part, mask, cov, attn, covnew, astr);
  k_ctx<<<dim3(32, BB), 256, 0, stream>>>(enc_out, attn, astr, partials);
  k_reduce<<<dim3(BB, 4), 256, 0, stream>>>(partials, ct, cts);
}